// Round 7
// baseline (2174.838 us; speedup 1.0000x reference)
//
#include <hip/hip_runtime.h>

typedef __attribute__((ext_vector_type(8))) short short8;
typedef __attribute__((ext_vector_type(4))) float f32x4;

constexpr int Bz = 64, Sz = 256, Tz = 32, Ez = 512, Hz = 512, G4 = 2048, VT = 32000;
constexpr int STEPS = Sz + Tz;          // 288 total recurrence steps per layer
constexpr int SLOT  = Bz * Hz;          // 32768 u16 per ring slot

__device__ __forceinline__ unsigned short f2b(float f) {
    unsigned u; __builtin_memcpy(&u, &f, 4);
    u = (u + 0x7fffu + ((u >> 16) & 1u)) >> 16;   // RNE fp32 -> bf16
    return (unsigned short)u;
}
__device__ __forceinline__ float sgm(float x) { return 1.0f / (1.0f + __expf(-x)); }
__device__ __forceinline__ float tnh(float x) { return 1.0f - 2.0f / (1.0f + __expf(2.0f * x)); }

// ===================== 0) workspace init =====================
// hbuf ring: [2 lay][4 slot][64][512] bf16. Only slot 3 (= step -1) must be zero.
__global__ __launch_bounds__(256) void init_kernel(
    unsigned* __restrict__ hbuf_u32, float* __restrict__ row_sums,
    unsigned* __restrict__ bars)
{
    const int idx = blockIdx.x * 256 + threadIdx.x;    // 128 blocks -> 32768 threads
    const int l = idx >> 14, off = idx & 16383;        // 16384 u32 per slot
    hbuf_u32[(l ? 7 * 16384 : 3 * 16384) + off] = 0u;  // zero slot3 of both layers
    if (blockIdx.x == 0) {
        if (threadIdx.x < 128) bars[threadIdx.x] = 0u; // [4 bt][32] flags
        if (threadIdx.x < 64) row_sums[threadIdx.x] = 0.0f;
    }
}

// ===================== 1) LSTM scan: dependency-flag pipeline =====================
// 128 blocks x 512 thr: block = (lay, bt, g). g covers 32 hidden units.
// Flags[bt][lay*16+g] = completed steps (monotone). No global barrier.
// L0 @ t waits: all L0 flags >= t, all L1 flags >= t-3 (ring depth 4).
// L1 @ t waits: all L0 flags >= t+1, all L1 flags >= t.
__global__ __launch_bounds__(512) void scan_kernel(
    const int* __restrict__ X, const int* __restrict__ Y,
    const float* __restrict__ emb_src, const float* __restrict__ emb_tgt,
    const float* __restrict__ eWih, const float* __restrict__ eWhh,
    const float* __restrict__ ebih, const float* __restrict__ ebhh,
    const float* __restrict__ dWih, const float* __restrict__ dWhh,
    const float* __restrict__ dbih, const float* __restrict__ dbhh,
    unsigned short* __restrict__ hbuf,
    unsigned* __restrict__ bars)
{
    __shared__ __align__(16) unsigned char smem[43264];
    unsigned short* xh_lds = (unsigned short*)smem;          // [16][1032] bf16 (pad +8)
    float* gates_lds = (float*)(smem + 33024);               // [4][16][32]
    float* c_lds     = (float*)(smem + 33024 + 8192);        // [16][32] fp32, persists

    const int tid  = threadIdx.x;
    const int bid  = blockIdx.x;
    const int lay  = bid >> 6;          // 0..1
    const int bt   = (bid >> 4) & 3;    // 0..3
    const int g    = bid & 15;          // unit tile: 32 units
    const int wave = tid >> 6, lane = tid & 63;
    const int gate = wave >> 1, sub = wave & 1;    // 2 waves per gate
    const int nl   = lane & 15, quad = lane >> 4;
    const int srow = tid >> 5, ssub = tid & 31;    // staging: 16 rows x 32 chunks(64B)
    const int bgrow = bt * 16 + srow;

    unsigned* fb = bars + bt * 32;      // this bt's 32 flags (16 L0 | 16 L1)
    const int myflag = lay * 16 + g;

    c_lds[tid] = 0.0f;                  // 512 fp32 cell states (16x32)
    __syncthreads();

    // ---- weight cache in VGPRs: 16 gate-rows x K=1024 (Wih||Whh), bf16 ----
    short8 wfrag[32];
    float bias_r = 0.0f;
    const int r = gate * 512 + g * 32 + sub * 16 + nl;   // global gate-row

    auto load_w = [&](const float* Wih, const float* Whh,
                      const float* bih, const float* bhh) {
        const float* wi = Wih + (size_t)(lay * G4 + r) * 512;
        const float* wh = Whh + (size_t)(lay * G4 + r) * 512;
#pragma unroll
        for (int kc = 0; kc < 32; ++kc) {
            const int k0 = kc * 32 + quad * 8;
            const float* s = (k0 < 512) ? (wi + k0) : (wh + (k0 - 512));
            short8 v;
#pragma unroll
            for (int j = 0; j < 8; ++j) v[j] = (short)f2b(s[j]);
            wfrag[kc] = v;
        }
        bias_r = bih[lay * G4 + r] + bhh[lay * G4 + r];
    };

    // L0 x prefetch (x-stager threads only): 32 fp32 -> 32 bf16 regs
    short8 xr[4];
    auto prefetch_x = [&](int tn) {
        int tok; const float* base;
        if (tn < Sz)       { tok = X[bgrow * Sz + tn]; base = emb_src; }
        else if (tn == Sz) { tok = 2;                  base = emb_tgt; }   // BOS
        else               { tok = Y[bgrow * Tz + (tn - Sz - 1)]; base = emb_tgt; }
        const float4* xs = (const float4*)(base + (size_t)tok * Ez + ssub * 32);
#pragma unroll
        for (int i = 0; i < 4; ++i) {
            float4 lo = xs[2 * i], hi = xs[2 * i + 1];
            short8 v;
            v[0] = (short)f2b(lo.x); v[1] = (short)f2b(lo.y);
            v[2] = (short)f2b(lo.z); v[3] = (short)f2b(lo.w);
            v[4] = (short)f2b(hi.x); v[5] = (short)f2b(hi.y);
            v[6] = (short)f2b(hi.z); v[7] = (short)f2b(hi.w);
            xr[i] = v;
        }
    };

    auto hring = [&](int l, int slot) { return hbuf + (size_t)(l * 4 + slot) * SLOT; };

    load_w(eWih, eWhh, ebih, ebhh);
    if (lay == 0 && ssub < 16) prefetch_x(0);

    for (int t = 0; t < STEPS; ++t) {
        if (t == Sz) load_w(dWih, dWhh, dbih, dbhh);   // overlaps the wait below

        // ---- wait on dependency flags (one-hop; wave 0 polls 32 flags in one load) ----
        unsigned thrL0, thrL1;
        if (lay == 0) { thrL0 = (unsigned)t;       thrL1 = (t >= 3) ? (unsigned)(t - 3) : 0u; }
        else          { thrL0 = (unsigned)(t + 1); thrL1 = (unsigned)t; }
        if (wave == 0) {
            unsigned thr = (lane < 16) ? thrL0 : thrL1;
            if (lane >= 32) thr = 0u;
            while (__ballot(__hip_atomic_load(fb + (lane & 31), __ATOMIC_RELAXED,
                                __HIP_MEMORY_SCOPE_AGENT) >= thr) != ~0ull)
                __builtin_amdgcn_s_sleep(1);
        }
        __syncthreads();

        // ---- stage x||h -> LDS ----
        {
            unsigned short* d = xh_lds + srow * 1032;
            if (ssub < 16) {          // x half
                if (lay == 0) {
                    short8* dx = (short8*)(d + ssub * 32);
#pragma unroll
                    for (int i = 0; i < 4; ++i) dx[i] = xr[i];
                } else {              // x = h(0, t) from ring slot t&3
                    const unsigned long long* xs = (const unsigned long long*)
                        (hring(0, t & 3) + bgrow * 512 + ssub * 32);
                    unsigned long long* dq = (unsigned long long*)(d + ssub * 32);
#pragma unroll
                    for (int i = 0; i < 8; ++i)
                        dq[i] = __hip_atomic_load(xs + i, __ATOMIC_RELAXED,
                                                  __HIP_MEMORY_SCOPE_AGENT);
                }
            } else {                  // h half: h(lay, t-1) from slot (t+3)&3
                const int hc = ssub - 16;
                const unsigned long long* hs = (const unsigned long long*)
                    (hring(lay, (t + 3) & 3) + bgrow * 512 + hc * 32);
                unsigned long long* dq = (unsigned long long*)(d + 512 + hc * 32);
#pragma unroll
                for (int i = 0; i < 8; ++i)
                    dq[i] = __hip_atomic_load(hs + i, __ATOMIC_RELAXED,
                                              __HIP_MEMORY_SCOPE_AGENT);
            }
        }
        __syncthreads();

        // ---- gates = [16 batch x 16 rows] MFMA, K=1024, 2 acc chains ----
        f32x4 a0 = {0.f, 0.f, 0.f, 0.f}, a1 = {0.f, 0.f, 0.f, 0.f};
        const unsigned short* ar = xh_lds + nl * 1032 + quad * 8;   // A[m=nl][k]
#pragma unroll
        for (int kc = 0; kc < 32; kc += 2) {
            short8 av0 = *(const short8*)(ar + kc * 32);
            short8 av1 = *(const short8*)(ar + (kc + 1) * 32);
            a0 = __builtin_amdgcn_mfma_f32_16x16x32_bf16(av0, wfrag[kc],     a0, 0, 0, 0);
            a1 = __builtin_amdgcn_mfma_f32_16x16x32_bf16(av1, wfrag[kc + 1], a1, 0, 0, 0);
        }
#pragma unroll
        for (int i = 0; i < 4; ++i) {
            float v = a0[i] + a1[i] + bias_r;
            v = (gate == 2) ? tnh(v) : sgm(v);
            gates_lds[gate * 512 + (quad * 4 + i) * 32 + sub * 16 + nl] = v;
        }
        __syncthreads();

        // ---- c/h update + h store to ring (sc1/LLC) ----
        if (tid < 256) {
            const int m = tid >> 4, np = tid & 15;
            float hp[2];
#pragma unroll
            for (int j = 0; j < 2; ++j) {
                const int n = 2 * np + j;
                const float iv = gates_lds[       m * 32 + n];
                const float fv = gates_lds[512  + m * 32 + n];
                const float gv = gates_lds[1024 + m * 32 + n];
                const float ov = gates_lds[1536 + m * 32 + n];
                float c = c_lds[m * 32 + n];
                c = fv * c + iv * gv;
                c_lds[m * 32 + n] = c;
                hp[j] = ov * tnh(c);
            }
            const unsigned pack = (unsigned)f2b(hp[0]) | ((unsigned)f2b(hp[1]) << 16);
            unsigned* dst = (unsigned*)(hring(lay, t & 3) +
                                        (bt * 16 + m) * 512 + g * 32 + 2 * np);
            __hip_atomic_store(dst, pack, __ATOMIC_RELAXED, __HIP_MEMORY_SCOPE_AGENT);
        }
        asm volatile("s_waitcnt vmcnt(0)" ::: "memory");   // h stores ack'd at LLC
        __syncthreads();
        if (tid == 0)
            __hip_atomic_store(fb + myflag, (unsigned)(t + 1),
                               __ATOMIC_RELAXED, __HIP_MEMORY_SCOPE_AGENT);
        if (lay == 0 && ssub < 16 && t + 1 < STEPS)
            prefetch_x(t + 1);       // overlaps next round's flag wait
    }
    // L1 final h(1,287) sits in ring slot 3 -> hbuf + 7*SLOT; FC reads it.
}

// ===================== 2) FC [64 x 32000] + exp-sum (logits -> out) =====================
__global__ __launch_bounds__(256) void fc_kernel(
    const float* __restrict__ fcW, const float* __restrict__ fcb,
    const unsigned short* __restrict__ hbuf,
    float* __restrict__ logits, float* __restrict__ row_sums)
{
    __shared__ __align__(16) unsigned char smem[66816];
    unsigned short* h_lds = (unsigned short*)smem;          // [64][520] bf16
    float* row_part = (float*)(smem + 64 * 520 * 2);        // [64]

    const int tid  = threadIdx.x;
    const int bid  = blockIdx.x;
    const int wave = tid >> 6;
    const int lane = tid & 63;
    const int nl   = lane & 15;
    const int quad = lane >> 4;

    {   // stage top hidden: ring slot (1,3) = hbuf + 7*SLOT
        const unsigned short* htop = hbuf + (size_t)7 * SLOT;
        const int rr2 = tid >> 2, pp = tid & 3;
        const short8* s = (const short8*)(htop + rr2 * 512 + pp * 128);
        short8* d = (short8*)(h_lds + rr2 * 520 + pp * 128);
#pragma unroll
        for (int i = 0; i < 16; ++i) d[i] = s[i];
    }
    if (tid < 64) row_part[tid] = 0.f;
    __syncthreads();

    const int c0 = bid * 128;                 // this block's 128 vocab cols
    f32x4 acc[8];
#pragma unroll
    for (int ct = 0; ct < 8; ++ct) acc[ct] = (f32x4){0.f, 0.f, 0.f, 0.f};
    const unsigned short* ar = h_lds + (wave * 16 + nl) * 520 + quad * 8;
    const float* bb = fcW + ((size_t)c0 + nl) * 512 + quad * 8;
    for (int kc = 0; kc < 16; ++kc) {
        short8 a = *(const short8*)(ar + kc * 32);
#pragma unroll
        for (int ct = 0; ct < 8; ++ct) {
            const float* bp = bb + (size_t)ct * 16 * 512 + kc * 32;
            float4 lo = *(const float4*)(bp);
            float4 hi = *(const float4*)(bp + 4);
            short8 b;
            b[0] = (short)f2b(lo.x); b[1] = (short)f2b(lo.y);
            b[2] = (short)f2b(lo.z); b[3] = (short)f2b(lo.w);
            b[4] = (short)f2b(hi.x); b[5] = (short)f2b(hi.y);
            b[6] = (short)f2b(hi.z); b[7] = (short)f2b(hi.w);
            acc[ct] = __builtin_amdgcn_mfma_f32_16x16x32_bf16(a, b, acc[ct], 0, 0, 0);
        }
    }
    float ls[4] = {0.f, 0.f, 0.f, 0.f};
#pragma unroll
    for (int ct = 0; ct < 8; ++ct) {
        const int col = c0 + ct * 16 + nl;
        const float bias = fcb[col];
#pragma unroll
        for (int i = 0; i < 4; ++i) {
            const float lg = acc[ct][i] + bias;
            logits[(size_t)(wave * 16 + quad * 4 + i) * VT + col] = lg;
            ls[i] += __expf(lg);     // |logit| <= ~41 -> no overflow
        }
    }
#pragma unroll
    for (int i = 0; i < 4; ++i)
        atomicAdd(&row_part[wave * 16 + quad * 4 + i], ls[i]);
    __syncthreads();
    if (tid < 64) atomicAdd(&row_sums[tid], row_part[tid]);
}

// ===================== 3) normalize in-place: out -= log(sum) =====================
__global__ __launch_bounds__(256) void norm_kernel(
    const float* __restrict__ row_sums, float* __restrict__ out)
{
    const int idx = blockIdx.x * 256 + threadIdx.x;   // grid covers 64*32000 exactly
    const int row = idx / VT;
    out[idx] = out[idx] - __logf(row_sums[row]);
}

extern "C" void kernel_launch(void* const* d_in, const int* in_sizes, int n_in,
                              void* d_out, int out_size, void* d_ws, size_t ws_size,
                              hipStream_t stream) {
    const int* X = (const int*)d_in[0];
    const int* Y = (const int*)d_in[1];
    const float* emb_src = (const float*)d_in[2];
    const float* emb_tgt = (const float*)d_in[3];
    const float* eWih = (const float*)d_in[4];
    const float* eWhh = (const float*)d_in[5];
    const float* ebih = (const float*)d_in[6];
    const float* ebhh = (const float*)d_in[7];
    const float* dWih = (const float*)d_in[8];
    const float* dWhh = (const float*)d_in[9];
    const float* dbih = (const float*)d_in[10];
    const float* dbhh = (const float*)d_in[11];
    const float* fcW = (const float*)d_in[12];
    const float* fcb = (const float*)d_in[13];
    float* out = (float*)d_out;

    // ws: [0,512KB) h ring; [512KB,+256B) row_sums; [+512B) flags
    unsigned short* hbuf = (unsigned short*)d_ws;
    float* row_sums = (float*)((char*)d_ws + 524288);
    unsigned* bars  = (unsigned*)((char*)d_ws + 524544);

    init_kernel<<<dim3(128), dim3(256), 0, stream>>>((unsigned*)hbuf, row_sums, bars);

    void* args[] = {&X, &Y, &emb_src, &emb_tgt, &eWih, &eWhh, &ebih, &ebhh,
                    &dWih, &dWhh, &dbih, &dbhh, &hbuf, &bars};
    hipLaunchCooperativeKernel(reinterpret_cast<void*>(scan_kernel),
                               dim3(128), dim3(512), args, 0, stream);

    fc_kernel<<<dim3(VT / 128), dim3(256), 0, stream>>>(fcW, fcb, hbuf, out, row_sums);

    norm_kernel<<<dim3((Bz * VT) / 256), dim3(256), 0, stream>>>(row_sums, out);
}